// Round 14
// baseline (132.809 us; speedup 1.0000x reference)
//
#include <hip/hip_runtime.h>
#include <stdint.h>

#define B 128
#define F 8192
#define H 8192
#define S 4
#define K 32
#define L 3
#define C 100

// ---------------------------------------------------------------------------
// Pack x (B,F) float {0,1} -> PLANAR u32 bit tables xP[w][f], w = b>>5,
// bit = b & 31. 1024 blocks x 128 threads (8 f per block). Zeroes d_out.
// ---------------------------------------------------------------------------
__global__ void pack_x_kernel(const float* __restrict__ x, uint32_t* __restrict__ xP,
                              float* __restrict__ out) {
    const int zi = blockIdx.x * 128 + threadIdx.x;
    if (zi < B * C) out[zi] = 0.0f;

    const int b = threadIdx.x;           // 0..127
    const int wv = threadIdx.x >> 6;     // wave id (0,1)
    const int f0 = blockIdx.x * 8;
    const float4* xr = (const float4*)(x + (size_t)b * F + f0);
#pragma unroll
    for (int j = 0; j < 2; ++j) {
        const float4 v = xr[j];
        const uint64_t m0 = __ballot(v.x > 0.5f);
        const uint64_t m1 = __ballot(v.y > 0.5f);
        const uint64_t m2 = __ballot(v.z > 0.5f);
        const uint64_t m3 = __ballot(v.w > 0.5f);
        if ((threadIdx.x & 63) == 0) {
            const int f = f0 + 4 * j;
            uint32_t* lo = xP + (size_t)(2 * wv) * F;
            uint32_t* hi = xP + (size_t)(2 * wv + 1) * F;
            lo[f + 0] = (uint32_t)m0;  hi[f + 0] = (uint32_t)(m0 >> 32);
            lo[f + 1] = (uint32_t)m1;  hi[f + 1] = (uint32_t)(m1 >> 32);
            lo[f + 2] = (uint32_t)m2;  hi[f + 2] = (uint32_t)(m2 >> 32);
            lo[f + 3] = (uint32_t)m3;  hi[f + 3] = (uint32_t)(m3 >> 32);
        }
    }
}

__device__ __forceinline__ int load_threshold(const int* p) {
    // threshold is a tiny int; guard against the harness storing it as f32 bits
    int v = *p;
    if (v >= (1 << 23)) v = (int)__int_as_float(v);
    return v;
}

__device__ __forceinline__ uint32_t pack2(int i0, float s0, int i1, float s1) {
    const uint32_t a = (uint32_t)i0 | (((uint32_t)__float_as_int(s0) & 0x80000000u) >> 16);
    const uint32_t b = (uint32_t)i1 | (((uint32_t)__float_as_int(s1) & 0x80000000u) >> 16);
    return a | (b << 16);
}

// ---------------------------------------------------------------------------
// BIT-SLICED u32 layer, CACHE-GATHER variant: the 32 KiB w-plane stays in
// L1/L2 (shared read-only across 128 blocks) and is gathered directly from
// global; only isg (per-lane streamed idx/sign) is staged in LDS (u16 pack).
// LDS 21 KiB -> ~6 blocks/CU (24 waves/CU); no tab staging, one barrier.
// Block = 256 = 4 waves; wave = segment s; lane = h. blockIdx = hg*4 + w.
// ---------------------------------------------------------------------------
#define ISG_ST 40   // u16 units per row (32 + 8 pad) = 80 B

__global__ __launch_bounds__(256, 6)
void layer_kernel(const uint32_t* __restrict__ prevP,
                  const int* __restrict__ idx,
                  const float* __restrict__ signs,
                  uint32_t* __restrict__ outP,
                  const int* __restrict__ thrp) {
    __shared__ uint16_t isg[S * 64 * ISG_ST];   // 20 KiB
    __shared__ uint32_t fbuf[256];              // 1 KiB
    const int tid  = threadIdx.x;
    const int lane = tid & 63;
    const int sw   = tid >> 6;                  // wave = segment
    const int w    = blockIdx.x & 3;
    const int hg   = blockIdx.x >> 2;
    const int h    = hg * 64 + lane;
    const int thr  = load_threshold(thrp);
    const uint32_t* __restrict__ plane = prevP + (size_t)w * H;   // 32 KiB, L1/L2-hot

    // ---- isg staging: 8 elems -> one uint4 / thread / segment ----
    {
        const int hrow = tid >> 2;
        const int k0   = (tid & 3) * 8;                  // u16 index in row
#pragma unroll
        for (int s = 0; s < S; ++s) {
            const int4*   ib = (const int4*)(idx   + ((size_t)s * H + hg * 64) * K);
            const float4* sb = (const float4*)(signs + ((size_t)s * H + hg * 64) * K);
            const int4   ia = ib[2 * tid],  ic = ib[2 * tid + 1];
            const float4 sa = sb[2 * tid],  sc = sb[2 * tid + 1];
            uint4 pv;
            pv.x = pack2(ia.x, sa.x, ia.y, sa.y);
            pv.y = pack2(ia.z, sa.z, ia.w, sa.w);
            pv.z = pack2(ic.x, sc.x, ic.y, sc.y);
            pv.w = pack2(ic.z, sc.z, ic.w, sc.w);
            *(uint4*)(&isg[s * (64 * ISG_ST) + hrow * ISG_ST + k0]) = pv;
        }
    }
    __syncthreads();

    // ---- cache-gather + bit-sliced accumulate ----
    uint32_t A[6] = {0, 0, 0, 0, 0, 0};      // sum of a      (<=32)
    uint32_t P[6] = {0, 0, 0, 0, 0, 0};      // sum of a&pos  (<=32)
    const uint4* row4 = (const uint4*)(&isg[sw * (64 * ISG_ST) + lane * ISG_ST]);
#pragma unroll
    for (int r = 0; r < 4; ++r) {
        const uint4 q = row4[r];                         // 8 u16 elems
        const uint32_t vv[4] = {q.x, q.y, q.z, q.w};
        uint32_t ik[8], nm[8];
#pragma unroll
        for (int j = 0; j < 4; ++j) {
            ik[2 * j]     = vv[j] & 0x1FFFu;
            nm[2 * j]     = (uint32_t)((int32_t)(vv[j] << 16) >> 31);  // ~0 if neg
            ik[2 * j + 1] = (vv[j] >> 16) & 0x1FFFu;
            nm[2 * j + 1] = (uint32_t)((int32_t)vv[j] >> 31);
        }
        uint32_t a[8];
#pragma unroll
        for (int j = 0; j < 8; ++j) a[j] = plane[ik[j]];  // VMEM gather, L1/L2-hot
#pragma unroll
        for (int j = 0; j < 8; ++j) {
            const uint32_t pm = ~nm[j];                   // ~0 if positive
            uint32_t cc = a[j];
#pragma unroll
            for (int i = 0; i < 6; ++i) { const uint32_t t = A[i]; A[i] = t ^ cc; cc = t & cc; }
            cc = a[j] & pm;
#pragma unroll
            for (int i = 0; i < 6; ++i) { const uint32_t t = P[i]; P[i] = t ^ cc; cc = t & cc; }
        }
    }

    // ---- fired = (2P >= A + thr), 7-bit bit-sliced compare ----
    uint32_t Y[7];
    {
        uint32_t c = 0;
#pragma unroll
        for (int i = 0; i < 7; ++i) {
            const uint32_t ai = (i < 6) ? A[i] : 0u;
            const uint32_t bm = ((thr >> i) & 1) ? 0xFFFFFFFFu : 0u;
            const uint32_t t  = ai ^ bm;
            Y[i] = t ^ c;
            c = (ai & bm) | (t & c);
        }
    }
    uint32_t bw = 0;
#pragma unroll
    for (int i = 0; i < 7; ++i) {
        const uint32_t xx = (i >= 1) ? P[i - 1] : 0u;
        const uint32_t d  = xx ^ Y[i];
        bw = ((~xx) & Y[i]) | ((~d) & bw);
    }
    const uint32_t fired = ~bw;

    // ---- OR across the 4 segment-waves ----
    fbuf[sw * 64 + lane] = fired;
    __syncthreads();
    if (sw == 0) {
        const uint32_t f = fbuf[lane] | fbuf[64 + lane] |
                           fbuf[128 + lane] | fbuf[192 + lane];
        outP[(size_t)w * H + h] = f;             // coalesced 4B stores
    }
}

// ---------------------------------------------------------------------------
// out[b][c] = sum_l sum_h act[l][b][h] * wout[l][h][c], act in {0,1}.
// Wave = one b; lanes = c. Grid = 32 b-groups x 32 h-chunks = 1024 blocks.
// 2-deep batched set-bit walk keeps two wout-row loads in flight. [R13]
// ---------------------------------------------------------------------------
#define NHC 32
#define HCH (H / NHC)   // 256 h per chunk

__global__ void final_kernel(const uint32_t* __restrict__ actP,
                             const float* __restrict__ wout,
                             float* __restrict__ out) {
    const int lane = threadIdx.x & 63;
    const int wid  = threadIdx.x >> 6;          // 0..3
    const int hc   = blockIdx.x & (NHC - 1);
    const int bg   = blockIdx.x / NHC;          // 0..31
    const int b    = bg * 4 + wid;              // wave-uniform
    const int w32  = b >> 5;                    // uniform within wave
    const int bit  = b & 31;

    float acc0 = 0.0f, acc1 = 0.0f;
    const int c1 = 64 + lane;
    const bool c1v = (c1 < C);

    for (int l = 0; l < L; ++l) {
        const uint32_t* aT = actP + ((size_t)l * 4 + w32) * H;
        const float* wl = wout + (size_t)l * H * C;
        for (int r = 0; r < HCH / 64; ++r) {
            const int hbase = hc * HCH + r * 64;
            const uint32_t m = aT[hbase + lane];
            uint64_t hm = __ballot((m >> bit) & 1u);
            while (hm) {
                const int s0 = __ffsll((unsigned long long)hm) - 1;
                hm &= hm - 1;
                const float* wr0 = wl + (size_t)(hbase + s0) * C;
                if (hm) {
                    const int s1 = __ffsll((unsigned long long)hm) - 1;
                    hm &= hm - 1;
                    const float* wr1 = wl + (size_t)(hbase + s1) * C;
                    const float a0 = wr0[lane];
                    const float a1 = wr1[lane];
                    const float b0 = c1v ? wr0[c1] : 0.0f;
                    const float b1 = c1v ? wr1[c1] : 0.0f;
                    acc0 += a0 + a1;
                    acc1 += b0 + b1;
                } else {
                    acc0 += wr0[lane];
                    if (c1v) acc1 += wr0[c1];
                }
            }
        }
    }
    atomicAdd(&out[b * C + lane], acc0);
    if (c1v) atomicAdd(&out[b * C + c1], acc1);
}

// ---------------------------------------------------------------------------
extern "C" void kernel_launch(void* const* d_in, const int* in_sizes, int n_in,
                              void* d_out, int out_size, void* d_ws, size_t ws_size,
                              hipStream_t stream) {
    const float* x      = (const float*)d_in[0];   // (B,F)
    const float* signs0 = (const float*)d_in[1];   // (S,H,K)
    const float* signsH = (const float*)d_in[2];   // (L-1,S,H,K)
    const float* wout   = (const float*)d_in[3];   // (L,H,C)
    const int*   idx0   = (const int*)d_in[4];     // (S,H,K)
    const int*   idxH   = (const int*)d_in[5];     // (L-1,S,H,K)
    const int*   thr    = (const int*)d_in[6];     // scalar
    float* out = (float*)d_out;                    // (B,C)

    // Workspace (planar u32): xP [4][F] (128 KiB), actP [L][4][H] (384 KiB)
    uint32_t* xP   = (uint32_t*)d_ws;
    uint32_t* actP = xP + (size_t)4 * F;

    // pack x + zero out (fused)
    pack_x_kernel<<<1024, 128, 0, stream>>>(x, xP, out);

    // layers: grid = 128 h-groups x 4 words = 512 blocks, 4 segment-waves each
    layer_kernel<<<512, 256, 0, stream>>>(xP, idx0, signs0, actP, thr);
    layer_kernel<<<512, 256, 0, stream>>>(actP, idxH, signsH,
                                          actP + (size_t)4 * H, thr);
    layer_kernel<<<512, 256, 0, stream>>>(actP + (size_t)4 * H,
                                          idxH + (size_t)S * H * K,
                                          signsH + (size_t)S * H * K,
                                          actP + (size_t)8 * H, thr);

    final_kernel<<<32 * NHC, 256, 0, stream>>>(actP, wout, out);
}